// Round 1
// baseline (237.987 us; speedup 1.0000x reference)
//
#include <hip/hip_runtime.h>

#define B_SZ 32
#define D_CH 96
#define H_SZ 64
#define W_SZ 64
#define L_SZ 4096   // H_SZ * W_SZ
#define N_ST 4
#define R_RK 6

static __device__ __forceinline__ float softplus_f(float v) {
    // matches jax.nn.softplus = logaddexp(v, 0)
    return fmaxf(v, 0.0f) + log1pf(expf(-fabsf(v)));
}

// ---------------------------------------------------------------------------
// Kernel 1: depthwise 5x5 conv (pad=2, cross-correlation) + bias + SiLU
// one block per (b,d) 64x64 image; 68x68 halo tile in LDS; 16 px/thread
// ---------------------------------------------------------------------------
__global__ __launch_bounds__(256) void conv_silu_kernel(
    const float* __restrict__ x, const float* __restrict__ conv_w,
    const float* __restrict__ conv_b, float* __restrict__ xs)
{
    __shared__ float tile[68 * 68];
    const int t = threadIdx.x;
    const int bd = blockIdx.x;
    const int d = bd % D_CH;
    const float* img = x + (size_t)bd * L_SZ;

    // per-channel weights: d is block-uniform -> scalar loads
    float wreg[25];
#pragma unroll
    for (int i = 0; i < 25; ++i) wreg[i] = conv_w[d * 25 + i];
    const float bias = conv_b[d];

    for (int i = t; i < 68 * 68; i += 256) {
        const int lh = i / 68, lw = i - lh * 68;
        const int gh = lh - 2, gw = lw - 2;
        float v = 0.0f;
        if (gh >= 0 && gh < H_SZ && gw >= 0 && gw < W_SZ) v = img[gh * W_SZ + gw];
        tile[i] = v;
    }
    __syncthreads();

    float* out = xs + (size_t)bd * L_SZ;
#pragma unroll
    for (int k = 0; k < 16; ++k) {
        const int p = t + k * 256;
        const int h = p >> 6, w = p & 63;
        float acc = bias;
#pragma unroll
        for (int kh = 0; kh < 5; ++kh)
#pragma unroll
            for (int kw = 0; kw < 5; ++kw)
                acc += wreg[kh * 5 + kw] * tile[(h + kh) * 68 + (w + kw)];
        const float sig = 1.0f / (1.0f + expf(-acc));
        out[p] = acc * sig;
    }
}

// ---------------------------------------------------------------------------
// Kernel 2: x_dbl[b,k,l] = sum_d x_proj_w[k,d] * xs[b,d,l]   (k = 0..13)
// block = one b, 256 consecutive l; loop over d with scalarized weights
// ---------------------------------------------------------------------------
__global__ __launch_bounds__(256) void proj_kernel(
    const float* __restrict__ xs, const float* __restrict__ x_proj_w,
    float* __restrict__ x_dbl)
{
    const int t = threadIdx.x;
    const int b = blockIdx.x >> 4;
    const int l = ((blockIdx.x & 15) << 8) + t;
    const float* xsb = xs + (size_t)b * D_CH * L_SZ + l;

    float acc[14];
#pragma unroll
    for (int k = 0; k < 14; ++k) acc[k] = 0.0f;

#pragma unroll 4
    for (int d = 0; d < D_CH; ++d) {
        const float xv = xsb[(size_t)d * L_SZ];
#pragma unroll
        for (int k = 0; k < 14; ++k)
            acc[k] += x_proj_w[k * D_CH + d] * xv;   // uniform -> s_load
    }

    float* out = x_dbl + (size_t)b * 14 * L_SZ + l;
#pragma unroll
    for (int k = 0; k < 14; ++k) out[(size_t)k * L_SZ] = acc[k];
}

// ---------------------------------------------------------------------------
// block-wide exclusive prefix sum over per-thread totals (256 threads, 4 waves)
// ---------------------------------------------------------------------------
static __device__ __forceinline__ float block_excl_scan(float local_sum,
                                                        float* wsum, int t)
{
    const int lane = t & 63;
    const int wid = t >> 6;
    float incl = local_sum;
#pragma unroll
    for (int off = 1; off < 64; off <<= 1) {
        const float u = __shfl_up(incl, (unsigned)off, 64);
        if (lane >= off) incl += u;
    }
    if (lane == 63) wsum[wid] = incl;
    float ex = __shfl_up(incl, 1u, 64);
    if (lane == 0) ex = 0.0f;
    __syncthreads();
    float wp = 0.0f;
#pragma unroll
    for (int w = 0; w < 4; ++w)
        if (w < wid) wp += wsum[w];
    __syncthreads();   // protect wsum for next call
    return wp + ex;
}

// ---------------------------------------------------------------------------
// Kernel 3: selective scan, replicating the reference's cumsum-trick exactly.
// one block per (b,d); thread t owns l = t*16 .. t*16+15 (contiguous).
// Reads xs row and writes y row in-place (thread-private range) -> xs may
// live in d_out.
// ---------------------------------------------------------------------------
__global__ __launch_bounds__(256) void scan_kernel(
    const float* __restrict__ xs, const float* __restrict__ x_dbl,
    const float* __restrict__ dt_w, const float* __restrict__ dt_b,
    const float* __restrict__ A_logs, const float* __restrict__ Ds,
    float* __restrict__ y)
{
    constexpr float EPS_F = 1e-9f;
    constexpr float LOG_EPS_F = -20.723265836946414f;  // ln(1e-9)

    __shared__ float wsum[4];
    const int t = threadIdx.x;
    const int bd = blockIdx.x;
    const int b = bd / D_CH;
    const int d = bd - b * D_CH;
    const int l0 = t * 16;

    const float* xs_row = xs + (size_t)bd * L_SZ + l0;
    const float* xd = x_dbl + (size_t)b * 14 * L_SZ + l0;

    float xv[16], dl[16], yac[16];
#pragma unroll
    for (int i = 0; i < 4; ++i) {
        const float4 v = ((const float4*)xs_row)[i];
        xv[4*i+0] = v.x; xv[4*i+1] = v.y; xv[4*i+2] = v.z; xv[4*i+3] = v.w;
    }

    const float dtb = dt_b[d];
#pragma unroll
    for (int i = 0; i < 16; ++i) { dl[i] = dtb; yac[i] = 0.0f; }
#pragma unroll
    for (int r = 0; r < R_RK; ++r) {
        const float wr = dt_w[d * R_RK + r];          // uniform -> s_load
        const float* row = xd + (size_t)r * L_SZ;
#pragma unroll
        for (int i = 0; i < 4; ++i) {
            const float4 v = ((const float4*)row)[i];
            dl[4*i+0] += wr * v.x; dl[4*i+1] += wr * v.y;
            dl[4*i+2] += wr * v.z; dl[4*i+3] += wr * v.w;
        }
    }
#pragma unroll
    for (int i = 0; i < 16; ++i) dl[i] = softplus_f(dl[i]);

    for (int n = 0; n < N_ST; ++n) {
        const float An = -expf(A_logs[d * N_ST + n]);  // uniform

        // ---- cumsum of log_dA -> S; P = exp(S) ----
        float sarr[16];
        float run = 0.0f;
#pragma unroll
        for (int i = 0; i < 16; ++i) {
            run += fmaxf(dl[i] * An, LOG_EPS_F);
            sarr[i] = run;
        }
        const float ex1 = block_excl_scan(run, wsum, t);
        float P[16];
#pragma unroll
        for (int i = 0; i < 16; ++i) P[i] = expf(sarr[i] + ex1);

        // ---- cumsum of dB_u / max(P, EPS) -> C; hs = P*C ----
        const float* Brow = xd + (size_t)(R_RK + n) * L_SZ;
        float carr[16];
        run = 0.0f;
#pragma unroll
        for (int i = 0; i < 4; ++i) {
            const float4 v = ((const float4*)Brow)[i];
            const float bb[4] = {v.x, v.y, v.z, v.w};
#pragma unroll
            for (int j = 0; j < 4; ++j) {
                const int idx = 4*i + j;
                run += dl[idx] * bb[j] * xv[idx] / fmaxf(P[idx], EPS_F);
                carr[idx] = run;
            }
        }
        const float ex2 = block_excl_scan(run, wsum, t);

        const float* Crow = xd + (size_t)(R_RK + N_ST + n) * L_SZ;
#pragma unroll
        for (int i = 0; i < 4; ++i) {
            const float4 v = ((const float4*)Crow)[i];
            const float cc[4] = {v.x, v.y, v.z, v.w};
#pragma unroll
            for (int j = 0; j < 4; ++j) {
                const int idx = 4*i + j;
                yac[idx] += (P[idx] * (carr[idx] + ex2)) * cc[j];
            }
        }
    }

    const float dsd = Ds[d];
    float* yrow = y + (size_t)bd * L_SZ + l0;
#pragma unroll
    for (int i = 0; i < 4; ++i) {
        float4 v;
        v.x = yac[4*i+0] + xv[4*i+0] * dsd;
        v.y = yac[4*i+1] + xv[4*i+1] * dsd;
        v.z = yac[4*i+2] + xv[4*i+2] * dsd;
        v.w = yac[4*i+3] + xv[4*i+3] * dsd;
        ((float4*)yrow)[i] = v;
    }
}

// ---------------------------------------------------------------------------
extern "C" void kernel_launch(void* const* d_in, const int* in_sizes, int n_in,
                              void* d_out, int out_size, void* d_ws, size_t ws_size,
                              hipStream_t stream)
{
    const float* x        = (const float*)d_in[0];
    const float* conv_w   = (const float*)d_in[1];
    const float* conv_b   = (const float*)d_in[2];
    const float* x_proj_w = (const float*)d_in[3];
    const float* dt_w     = (const float*)d_in[4];
    const float* dt_b     = (const float*)d_in[5];
    const float* A_logs   = (const float*)d_in[6];
    const float* Ds       = (const float*)d_in[7];

    float* y     = (float*)d_out;
    float* xs    = y;                 // stage conv output in d_out; scan reads
                                      // and overwrites it thread-privately
    float* x_dbl = (float*)d_ws;      // 32*14*4096 floats = 7.34 MB

    conv_silu_kernel<<<B_SZ * D_CH, 256, 0, stream>>>(x, conv_w, conv_b, xs);
    proj_kernel<<<B_SZ * (L_SZ / 256), 256, 0, stream>>>(xs, x_proj_w, x_dbl);
    scan_kernel<<<B_SZ * D_CH, 256, 0, stream>>>(xs, x_dbl, dt_w, dt_b,
                                                 A_logs, Ds, y);
}

// Round 2
// 202.235 us; speedup vs baseline: 1.1768x; 1.1768x over previous
//
#include <hip/hip_runtime.h>

#define B_SZ 32
#define D_CH 96
#define L_SZ 4096   // 64*64
#define N_ST 4
#define R_RK 6

static __device__ __forceinline__ float softplus_f(float v) {
    // logaddexp(v,0) with native exp/log; abs err < 1e-7 vs libm
    return fmaxf(v, 0.0f) + __logf(1.0f + __expf(-fabsf(v)));
}

// ---------------------------------------------------------------------------
// zero-fill x_dbl (proj accumulates with atomics)
// ---------------------------------------------------------------------------
__global__ __launch_bounds__(256) void zero_kernel(float4* __restrict__ p, int n4)
{
    const int i = blockIdx.x * 256 + threadIdx.x;
    if (i < n4) p[i] = make_float4(0.f, 0.f, 0.f, 0.f);
}

// ---------------------------------------------------------------------------
// Kernel 1: depthwise 5x5 conv (pad=2) + bias + SiLU
// one block per (b,d); 68x68 halo tile, vectorized fill; 16 px/thread
// ---------------------------------------------------------------------------
__global__ __launch_bounds__(256) void conv_silu_kernel(
    const float* __restrict__ x, const float* __restrict__ conv_w,
    const float* __restrict__ conv_b, float* __restrict__ xs)
{
    __shared__ float tile[68 * 68];
    const int t = threadIdx.x;
    const int bd = blockIdx.x;
    const int d = bd % D_CH;
    const float* img = x + bd * L_SZ;

    float wreg[25];
#pragma unroll
    for (int i = 0; i < 25; ++i) wreg[i] = conv_w[d * 25 + i];
    const float bias = conv_b[d];

    // zero whole tile (float4): 68*68/4 = 1156
    const float4 z4 = make_float4(0.f, 0.f, 0.f, 0.f);
    for (int i = t; i < 1156; i += 256) ((float4*)tile)[i] = z4;
    __syncthreads();
    // interior copy: 64 rows x 32 float2
    for (int i = t; i < 2048; i += 256) {
        const int r = i >> 5;
        const int c = (i & 31) << 1;
        const float2 v = *(const float2*)(img + (r << 6) + c);
        *(float2*)(tile + (r + 2) * 68 + 2 + c) = v;
    }
    __syncthreads();

    float* out = xs + bd * L_SZ;
#pragma unroll
    for (int k = 0; k < 16; ++k) {
        const int p = t + k * 256;
        const int h = p >> 6, w = p & 63;
        float acc = bias;
#pragma unroll
        for (int kh = 0; kh < 5; ++kh)
#pragma unroll
            for (int kw = 0; kw < 5; ++kw)
                acc += wreg[kh * 5 + kw] * tile[(h + kh) * 68 + (w + kw)];
        const float sig = __builtin_amdgcn_rcpf(1.0f + __expf(-acc));
        out[p] = acc * sig;
    }
}

// ---------------------------------------------------------------------------
// Kernel 2: x_dbl[b,k,l] += sum_{d in part} x_proj_w[k,d] * xs[b,d,l]
// grid = B * 16(l-chunks) * 4(d-parts); 24 d per block; atomic accumulate
// ---------------------------------------------------------------------------
__global__ __launch_bounds__(256) void proj_kernel(
    const float* __restrict__ xs, const float* __restrict__ x_proj_w,
    float* __restrict__ x_dbl)
{
    const int t = threadIdx.x;
    const int bi = blockIdx.x;
    const int part = bi & 3;
    const int chunk = (bi >> 2) & 15;
    const int b = bi >> 6;
    const int l = (chunk << 8) + t;
    const int d0 = part * 24;
    const float* xsb = xs + b * D_CH * L_SZ + d0 * L_SZ + l;

    float acc[14];
#pragma unroll
    for (int k = 0; k < 14; ++k) acc[k] = 0.0f;

#pragma unroll 8
    for (int dd = 0; dd < 24; ++dd) {
        const float xv = xsb[dd * L_SZ];
#pragma unroll
        for (int k = 0; k < 14; ++k)
            acc[k] += x_proj_w[k * D_CH + d0 + dd] * xv;   // uniform -> s_load
    }

    float* outp = x_dbl + b * 14 * L_SZ + l;
#pragma unroll
    for (int k = 0; k < 14; ++k) atomicAdd(outp + k * L_SZ, acc[k]);
}

// ---------------------------------------------------------------------------
// block-wide exclusive prefix sum over per-thread totals (512 threads, 8 waves)
// ---------------------------------------------------------------------------
static __device__ __forceinline__ float block_excl_scan(float local_sum,
                                                        float* wsum, int t)
{
    const int lane = t & 63;
    const int wid = t >> 6;
    float incl = local_sum;
#pragma unroll
    for (int off = 1; off < 64; off <<= 1) {
        const float u = __shfl_up(incl, (unsigned)off, 64);
        if (lane >= off) incl += u;
    }
    if (lane == 63) wsum[wid] = incl;
    float ex = __shfl_up(incl, 1u, 64);
    if (lane == 0) ex = 0.0f;
    __syncthreads();
    float wp = 0.0f;
#pragma unroll
    for (int w = 0; w < 7; ++w)
        if (w < wid) wp += wsum[w];
    __syncthreads();   // protect wsum for next call
    return wp + ex;
}

// ---------------------------------------------------------------------------
// Kernel 3: selective scan (reference cumsum-trick, exact formulation)
// one block per (b,d); 512 threads x 8 contiguous l each.
// no divides: 1/max(P,EPS) == min(exp(-S), 1e9)
// ---------------------------------------------------------------------------
__global__ __launch_bounds__(512, 4) void scan_kernel(
    const float* __restrict__ xs, const float* __restrict__ x_dbl,
    const float* __restrict__ dt_w, const float* __restrict__ dt_b,
    const float* __restrict__ A_logs, const float* __restrict__ Ds,
    float* __restrict__ y)
{
    constexpr float LOG_EPS_F = -20.723265836946414f;  // ln(1e-9)

    __shared__ float wsum[8];
    const int t = threadIdx.x;
    const int bd = blockIdx.x;
    const int b = bd / D_CH;
    const int d = bd - b * D_CH;
    const int l0 = t * 8;

    const float* xs_row = xs + bd * L_SZ + l0;
    const float* xd = x_dbl + b * 14 * L_SZ + l0;

    float xv[8], dl[8], yac[8];
#pragma unroll
    for (int i = 0; i < 2; ++i) {
        const float4 v = ((const float4*)xs_row)[i];
        xv[4*i+0] = v.x; xv[4*i+1] = v.y; xv[4*i+2] = v.z; xv[4*i+3] = v.w;
    }

    const float dtb = dt_b[d];
#pragma unroll
    for (int i = 0; i < 8; ++i) { dl[i] = dtb; yac[i] = 0.0f; }
#pragma unroll
    for (int r = 0; r < R_RK; ++r) {
        const float wr = dt_w[d * R_RK + r];          // uniform -> s_load
        const float* row = xd + r * L_SZ;
#pragma unroll
        for (int i = 0; i < 2; ++i) {
            const float4 v = ((const float4*)row)[i];
            dl[4*i+0] += wr * v.x; dl[4*i+1] += wr * v.y;
            dl[4*i+2] += wr * v.z; dl[4*i+3] += wr * v.w;
        }
    }
#pragma unroll
    for (int i = 0; i < 8; ++i) dl[i] = softplus_f(dl[i]);

    for (int n = 0; n < N_ST; ++n) {
        const float An = -__expf(A_logs[d * N_ST + n]);  // uniform

        // ---- cumsum of log_dA -> S; P = exp(S); Pinv = min(exp(-S),1e9) ----
        float P[8];
        float run = 0.0f;
#pragma unroll
        for (int i = 0; i < 8; ++i) {
            run += fmaxf(dl[i] * An, LOG_EPS_F);
            P[i] = run;                                  // holds local S
        }
        const float ex1 = block_excl_scan(run, wsum, t);

        // ---- cumsum of dB_u * Pinv ----
        const float* Brow = xd + (R_RK + n) * L_SZ;
        float carr[8];
        float run2 = 0.0f;
#pragma unroll
        for (int i = 0; i < 2; ++i) {
            const float4 v = ((const float4*)Brow)[i];
            const float bb[4] = {v.x, v.y, v.z, v.w};
#pragma unroll
            for (int j = 0; j < 4; ++j) {
                const int idx = 4*i + j;
                const float S = P[idx] + ex1;
                const float pinv = fminf(__expf(-S), 1e9f);
                P[idx] = __expf(S);
                run2 += dl[idx] * bb[j] * xv[idx] * pinv;
                carr[idx] = run2;
            }
        }
        const float ex2 = block_excl_scan(run2, wsum, t);

        const float* Crow = xd + (R_RK + N_ST + n) * L_SZ;
#pragma unroll
        for (int i = 0; i < 2; ++i) {
            const float4 v = ((const float4*)Crow)[i];
            const float cc[4] = {v.x, v.y, v.z, v.w};
#pragma unroll
            for (int j = 0; j < 4; ++j) {
                const int idx = 4*i + j;
                yac[idx] += (P[idx] * (carr[idx] + ex2)) * cc[j];
            }
        }
    }

    const float dsd = Ds[d];
    float* yrow = y + bd * L_SZ + l0;
#pragma unroll
    for (int i = 0; i < 2; ++i) {
        float4 v;
        v.x = yac[4*i+0] + xv[4*i+0] * dsd;
        v.y = yac[4*i+1] + xv[4*i+1] * dsd;
        v.z = yac[4*i+2] + xv[4*i+2] * dsd;
        v.w = yac[4*i+3] + xv[4*i+3] * dsd;
        ((float4*)yrow)[i] = v;
    }
}

// ---------------------------------------------------------------------------
extern "C" void kernel_launch(void* const* d_in, const int* in_sizes, int n_in,
                              void* d_out, int out_size, void* d_ws, size_t ws_size,
                              hipStream_t stream)
{
    const float* x        = (const float*)d_in[0];
    const float* conv_w   = (const float*)d_in[1];
    const float* conv_b   = (const float*)d_in[2];
    const float* x_proj_w = (const float*)d_in[3];
    const float* dt_w     = (const float*)d_in[4];
    const float* dt_b     = (const float*)d_in[5];
    const float* A_logs   = (const float*)d_in[6];
    const float* Ds       = (const float*)d_in[7];

    float* y     = (float*)d_out;
    float* xs    = y;                 // stage conv output in d_out; scan reads
                                      // and overwrites it thread-privately
    float* x_dbl = (float*)d_ws;      // 32*14*4096 floats = 7.34 MB

    const int n4 = B_SZ * 14 * L_SZ / 4;   // 458752 float4s
    zero_kernel<<<(n4 + 255) / 256, 256, 0, stream>>>((float4*)x_dbl, n4);
    conv_silu_kernel<<<B_SZ * D_CH, 256, 0, stream>>>(x, conv_w, conv_b, xs);
    proj_kernel<<<B_SZ * 16 * 4, 256, 0, stream>>>(xs, x_proj_w, x_dbl);
    scan_kernel<<<B_SZ * D_CH, 512, 0, stream>>>(xs, x_dbl, dt_w, dt_b,
                                                 A_logs, Ds, y);
}